// Round 11
// baseline (79.758 us; speedup 1.0000x reference)
//
#include <hip/hip_runtime.h>
#include <hip/hip_bf16.h>

typedef float    f32x4 __attribute__((ext_vector_type(4)));
typedef _Float16 f16x4 __attribute__((ext_vector_type(4)));
typedef _Float16 f16x8 __attribute__((ext_vector_type(8)));
typedef unsigned int   u32x4 __attribute__((ext_vector_type(4)));

#define NB 32
#define NA 64
#define NF 128
#define NC 128
#define NBLK 576

// ---------------------------------------------------------------------------
// Fused single-launch kernel. 576 blocks x 256 thr, 3 blocks/CU (all
// co-resident -> spin barrier is deadlock-free).
// Phase A (blocks 0..255): u/v for 16 atoms of (b,g,half) via f16 MFMA.
//         (blocks 256..263): w1f = W1 in MFMA A-fragment order.
// Device-wide barrier: agent-scope fences + atomic counter (zeroed per call
// by hipMemsetAsync -> deterministic).
// Phase B: block handles 2 pair-tasks (same batch); w_s staged once.
// ---------------------------------------------------------------------------
__global__ __launch_bounds__(256, 3) void fused_kernel(
    const float* __restrict__ x, const float* __restrict__ W0,
    const float* __restrict__ b0, const float* __restrict__ W1,
    const float* __restrict__ b1g, _Float16* __restrict__ u,
    _Float16* __restrict__ v, _Float16* __restrict__ w1f,
    unsigned int* __restrict__ cnt, float* __restrict__ out)
{
    __shared__ __align__(16) unsigned char smem[40960];
    _Float16* w0h = (_Float16*)smem;              // phase A: 32 KB frag-major
    _Float16* u_s = (_Float16*)smem;              // phase B: 4 KB
    _Float16* v_s = (_Float16*)(smem + 4096);     // phase B: 4 KB
    _Float16* w_s = (_Float16*)(smem + 8192);     // phase B: 32 KB

    int blk = blockIdx.x, tid = threadIdx.x;
    int lane = tid & 63, wave = tid >> 6;
    int llo = lane & 15, lhi = lane >> 4;
    f32x4 z = {0.f, 0.f, 0.f, 0.f};

    // ================= PHASE A =================
    if (blk < 256) {
        int b = blk >> 3, g = (blk >> 1) & 3, half = blk & 1;

        const float* xrow = x + ((size_t)b * NA + g * 16 + llo) * NF;
        f16x8 xf[4];
        #pragma unroll
        for (int kk = 0; kk < 4; ++kk) {
            f32x4 a0 = *(const f32x4*)(xrow + kk * 32 + lhi * 8);
            f32x4 a1 = *(const f32x4*)(xrow + kk * 32 + lhi * 8 + 4);
            #pragma unroll
            for (int e = 0; e < 4; ++e) {
                xf[kk][e]     = (_Float16)a0[e];
                xf[kk][e + 4] = (_Float16)a1[e];
            }
        }

        #pragma unroll
        for (int p = 0; p < 8; ++p) {
            int sl   = p * 256 + tid;
            int frag = sl >> 6;
            int ln   = sl & 63;
            int kk   = frag >> 3, nfc = frag & 7;
            int k0   = half * 128 + kk * 32 + (ln >> 4) * 8;
            int c    = nfc * 16 + (ln & 15);
            f16x8 o;
            #pragma unroll
            for (int e = 0; e < 8; ++e)
                o[e] = (_Float16)W0[(size_t)(k0 + e) * NC + c];
            *(f16x8*)(w0h + (size_t)sl * 8) = o;
        }
        __syncthreads();

        f32x4 acc[2];
        acc[0] = z; acc[1] = z;
        #pragma unroll
        for (int kk = 0; kk < 4; ++kk) {
            #pragma unroll
            for (int t = 0; t < 2; ++t) {
                int nfc = wave * 2 + t;
                f16x8 aw = *(const f16x8*)(w0h +
                    (size_t)((kk * 8 + nfc) * 64 + lane) * 8);
                acc[t] = __builtin_amdgcn_mfma_f32_16x16x32_f16(
                    aw, xf[kk], acc[t], 0, 0, 0);
            }
        }

        _Float16* dst = half ? v : u;
        size_t arow = ((size_t)b * NA + g * 16 + llo) * NC;
        #pragma unroll
        for (int t = 0; t < 2; ++t) {
            int nfc = wave * 2 + t;
            int c0  = nfc * 16 + lhi * 4;
            f16x4 o;
            if (half) {
                f32x4 bb = *(const f32x4*)(b0 + c0);
                #pragma unroll
                for (int e = 0; e < 4; ++e)
                    o[e] = (_Float16)(acc[t][e] + bb[e]);
            } else {
                #pragma unroll
                for (int e = 0; e < 4; ++e)
                    o[e] = (_Float16)acc[t][e];
            }
            *(f16x4*)(dst + arow + c0) = o;
        }
    } else if (blk < 264) {
        int fl   = (blk - 256) * 256 + tid;   // 0..2047
        int ln   = fl & 63;
        int frag = fl >> 6;                   // kk*8+nf
        int kk = frag >> 3, nf = frag & 7;
        int k0 = kk * 32 + (ln >> 4) * 8;
        int n  = nf * 16 + (ln & 15);
        f16x8 o;
        #pragma unroll
        for (int e = 0; e < 8; ++e)
            o[e] = (_Float16)W1[(size_t)(k0 + e) * NC + n];
        *(f16x8*)(w1f + (size_t)fl * 8) = o;
    }

    // ================= DEVICE BARRIER =================
    __syncthreads();
    if (tid == 0) {
        __builtin_amdgcn_fence(__ATOMIC_RELEASE, "agent");
        __hip_atomic_fetch_add(cnt, 1u, __ATOMIC_RELAXED,
                               __HIP_MEMORY_SCOPE_AGENT);
        while (__hip_atomic_load(cnt, __ATOMIC_RELAXED,
                                 __HIP_MEMORY_SCOPE_AGENT) < NBLK)
            __builtin_amdgcn_s_sleep(1);
        __builtin_amdgcn_fence(__ATOMIC_ACQUIRE, "agent");
    }
    __syncthreads();

    // ================= PHASE B =================
    // stage W1 frags once per block (2048 contiguous 16B chunks)
    #pragma unroll
    for (int p = 0; p < 8; ++p)
        ((u32x4*)w_s)[p * 256 + tid] = ((const u32x4*)w1f)[p * 256 + tid];

    #pragma unroll 1
    for (int s = 0; s < 2; ++s) {
        int task = blk * 2 + s;           // 0..1151, same b for s=0,1
        int b = task / 36;
        int t = task % 36;
        int I = 0;
        while (t >= 8 - I) { t -= 8 - I; ++I; }
        int J = I + t;

        if (s) __syncthreads();           // readers of previous tiles done

        // stage u/v tiles, swizzled: chunk = row*16 + (c ^ (row&7))
        {
            int row = tid >> 4;           // 0..15
            int c   = tid & 15;           // 16B chunk within 256B row
            int ga  = b * NA + ((row < 8) ? (I * 8 + row) : (J * 8 + (row & 7)));
            int sc  = row * 16 + (c ^ (row & 7));
            ((u32x4*)u_s)[sc] = ((const u32x4*)(u + (size_t)ga * NC))[c];
            ((u32x4*)v_s)[sc] = ((const u32x4*)(v + (size_t)ga * NC))[c];
        }
        __syncthreads();

        int r  = wave * 16 + llo;
        int il = r >> 3;                  // 0..7
        int jl = r & 7;                   // 0..7

        f32x4 acc0[8], acc1[8];
        #pragma unroll
        for (int nf = 0; nf < 8; ++nf) { acc0[nf] = z; acc1[nf] = z; }

        const f16x8* us = (const f16x8*)u_s;
        const f16x8* vs = (const f16x8*)v_s;
        const f16x8* wf = (const f16x8*)w_s;

        #pragma unroll
        for (int kk = 0; kk < 4; ++kk) {
            int kc  = kk * 4 + lhi;
            int scI = il * 16 + (kc ^ il);
            int scJ = (8 + jl) * 16 + (kc ^ jl);

            f16x8 uIv = us[scI];
            f16x8 vIv = vs[scI];
            f16x8 uJv = us[scJ];
            f16x8 vJv = vs[scJ];

            f16x8 s0 = uIv + vJv;
            f16x8 s1 = uJv + vIv;
            f16x8 h0, h1;
            #pragma unroll
            for (int e = 0; e < 8; ++e) {
                h0[e] = s0[e] < (_Float16)0 ? (_Float16)0 : s0[e];
                h1[e] = s1[e] < (_Float16)0 ? (_Float16)0 : s1[e];
            }

            #pragma unroll
            for (int nf = 0; nf < 8; ++nf) {
                f16x8 w = wf[(kk * 8 + nf) * 64 + lane];
                acc0[nf] = __builtin_amdgcn_mfma_f32_16x16x32_f16(
                    w, h0, acc0[nf], 0, 0, 0);
                acc1[nf] = __builtin_amdgcn_mfma_f32_16x16x32_f16(
                    w, h1, acc1[nf], 0, 0, 0);
            }
        }

        int Ig = I * 8 + il;
        int Jg = J * 8 + jl;
        float* p1 = out + ((size_t)b * 4096 + Ig * 64 + Jg) * 128 + lhi * 4;
        float* p2 = out + ((size_t)b * 4096 + Jg * 64 + Ig) * 128 + lhi * 4;
        bool mirror = (I != J);
        #pragma unroll
        for (int nf = 0; nf < 8; ++nf) {
            f32x4 bias = *(const f32x4*)(b1g + nf * 16 + lhi * 4);
            f32x4 val;
            #pragma unroll
            for (int e = 0; e < 4; ++e)
                val[e] = fmaxf(acc0[nf][e] + bias[e], 0.f) +
                         fmaxf(acc1[nf][e] + bias[e], 0.f);
            *(f32x4*)(p1 + nf * 16) = val;
            if (mirror)
                *(f32x4*)(p2 + nf * 16) = val;
        }
    }
}

extern "C" void kernel_launch(void* const* d_in, const int* in_sizes, int n_in,
                              void* d_out, int out_size, void* d_ws, size_t ws_size,
                              hipStream_t stream)
{
    (void)in_sizes; (void)n_in; (void)out_size; (void)ws_size;
    const float* x  = (const float*)d_in[0];
    const float* W0 = (const float*)d_in[1];
    const float* b0 = (const float*)d_in[2];
    const float* W1 = (const float*)d_in[3];
    const float* b1 = (const float*)d_in[4];
    float* out = (float*)d_out;

    _Float16* u   = (_Float16*)d_ws;                       // 0.5 MB
    _Float16* v   = u + (size_t)NB * NA * NC;              // 0.5 MB
    _Float16* w1f = v + (size_t)NB * NA * NC;              // 32 KB
    unsigned int* cnt = (unsigned int*)(w1f + 32 * 64 * 8);

    hipMemsetAsync(cnt, 0, sizeof(unsigned int), stream);
    fused_kernel<<<NBLK, 256, 0, stream>>>(x, W0, b0, W1, b1, u, v, w1f,
                                           cnt, out);
}

// Round 12
// 40.248 us; speedup vs baseline: 1.9817x; 1.9817x over previous
//
#include <hip/hip_runtime.h>
#include <hip/hip_bf16.h>

typedef float    f32x4 __attribute__((ext_vector_type(4)));
typedef _Float16 f16x4 __attribute__((ext_vector_type(4)));
typedef _Float16 f16x8 __attribute__((ext_vector_type(8)));
typedef unsigned int   u32x4 __attribute__((ext_vector_type(4)));

#define NB 32
#define NA 64
#define NF 128
#define NC 128

// ---------------------------------------------------------------------------
// prep:
//  blocks 0..255 (b,g,half): u or v for 16 atoms via f16 MFMA.
//    W0-half is staged into LDS via coalesced vector loads (f32->f16) in a
//    bank-XOR-swizzled [k][c] layout; A-frags are then built with cheap
//    conflict-free ds_read_u16 (was: 64 scalar VMEM loads/thread).
//  blocks 256..263: w1f = W1 in MFMA A-fragment order.
// ---------------------------------------------------------------------------
__global__ __launch_bounds__(256) void prep_kernel(
    const float* __restrict__ x, const float* __restrict__ W0,
    const float* __restrict__ b0, const float* __restrict__ W1,
    _Float16* __restrict__ u, _Float16* __restrict__ v,
    _Float16* __restrict__ w1f)
{
    int blk = blockIdx.x, tid = threadIdx.x;
    int lane = tid & 63, wave = tid >> 6;
    int llo = lane & 15, lhi = lane >> 4;

    if (blk < 256) {
        // [k][c] f16, 16B chunks XOR-swizzled by (k>>3)&7
        __shared__ __align__(16) _Float16 w0l[128 * 128];   // 32 KB
        int b = blk >> 3, g = (blk >> 1) & 3, half = blk & 1;

        // ---- x B-fragments from global (issued first, latency hidden)
        const float* xrow = x + ((size_t)b * NA + g * 16 + llo) * NF;
        f16x8 xf[4];
        #pragma unroll
        for (int kk = 0; kk < 4; ++kk) {
            f32x4 a0 = *(const f32x4*)(xrow + kk * 32 + lhi * 8);
            f32x4 a1 = *(const f32x4*)(xrow + kk * 32 + lhi * 8 + 4);
            #pragma unroll
            for (int e = 0; e < 4; ++e) {
                xf[kk][e]     = (_Float16)a0[e];
                xf[kk][e + 4] = (_Float16)a1[e];
            }
        }

        // ---- stage W0 half -> LDS (coalesced reads, swizzled 16B writes)
        const float* w0src = W0 + (size_t)half * 128 * NC;
        #pragma unroll
        for (int p = 0; p < 8; ++p) {
            int idx = p * 256 + tid;          // 0..2047 jobs of 8 elems
            int k   = idx >> 4;               // row 0..127
            int ch  = idx & 15;               // 16B chunk 0..15
            f32x4 a0 = *(const f32x4*)(w0src + (size_t)k * NC + ch * 8);
            f32x4 a1 = *(const f32x4*)(w0src + (size_t)k * NC + ch * 8 + 4);
            f16x8 o;
            #pragma unroll
            for (int e = 0; e < 4; ++e) {
                o[e]     = (_Float16)a0[e];
                o[e + 4] = (_Float16)a1[e];
            }
            int sc = (ch ^ ((k >> 3) & 7)) << 3;
            *(f16x8*)(w0l + k * 128 + sc) = o;
        }
        __syncthreads();

        // ---- A-frags from LDS (ds_read_u16, conflict-free) + 8 MFMAs
        f32x4 acc[2];
        f32x4 z = {0.f, 0.f, 0.f, 0.f};
        acc[0] = z; acc[1] = z;
        #pragma unroll
        for (int kk = 0; kk < 4; ++kk) {
            #pragma unroll
            for (int t = 0; t < 2; ++t) {
                int nfc = wave * 2 + t;
                int c   = nfc * 16 + llo;
                int chx = (c >> 3);           // chunk of c
                int cl  = c & 7;
                f16x8 aw;
                #pragma unroll
                for (int e = 0; e < 8; ++e) {
                    int k = kk * 32 + lhi * 8 + e;
                    int sc = ((chx ^ ((k >> 3) & 7)) << 3) | cl;
                    aw[e] = w0l[k * 128 + sc];
                }
                acc[t] = __builtin_amdgcn_mfma_f32_16x16x32_f16(
                    aw, xf[kk], acc[t], 0, 0, 0);
            }
        }

        // ---- store: D[c = nfc*16+lhi*4+q][atom = llo]
        _Float16* dst = half ? v : u;
        size_t arow = ((size_t)b * NA + g * 16 + llo) * NC;
        #pragma unroll
        for (int t = 0; t < 2; ++t) {
            int nfc = wave * 2 + t;
            int c0  = nfc * 16 + lhi * 4;
            f16x4 o;
            if (half) {
                f32x4 bb = *(const f32x4*)(b0 + c0);
                #pragma unroll
                for (int e = 0; e < 4; ++e)
                    o[e] = (_Float16)(acc[t][e] + bb[e]);
            } else {
                #pragma unroll
                for (int e = 0; e < 4; ++e)
                    o[e] = (_Float16)acc[t][e];
            }
            *(f16x4*)(dst + arow + c0) = o;
        }
    } else {
        int fl   = (blk - 256) * 256 + tid;   // 0..2047
        int ln   = fl & 63;
        int frag = fl >> 6;                   // kk*8+nf
        int kk = frag >> 3, nf = frag & 7;
        int k0 = kk * 32 + (ln >> 4) * 8;
        int n  = nf * 16 + (ln & 15);
        f16x8 o;
        #pragma unroll
        for (int e = 0; e < 8; ++e)
            o[e] = (_Float16)W1[(size_t)(k0 + e) * NC + n];
        *(f16x8*)(w1f + (size_t)fl * 8) = o;
    }
}

// ---------------------------------------------------------------------------
// main: 576 blocks x 256 thr, 4 blocks/CU (LDS 40KB*4 = 160KB), single
// dispatch round, zero tail. Each block: stage W1 frags once, then 2
// pair-tasks (same batch). Compute body identical to R9.
// ---------------------------------------------------------------------------
__global__ __launch_bounds__(256, 4) void pair_mlp_kernel(
    const float* __restrict__ b1g, const _Float16* __restrict__ u,
    const _Float16* __restrict__ v, const _Float16* __restrict__ w1f,
    float* __restrict__ out)
{
    __shared__ __align__(16) _Float16 u_s[16 * 128];    // 4 KB
    __shared__ __align__(16) _Float16 v_s[16 * 128];    // 4 KB
    __shared__ __align__(16) _Float16 w_s[32 * 64 * 8]; // 32 KB frag-major

    int blk = blockIdx.x, tid = threadIdx.x;
    int wave = tid >> 6, lane = tid & 63;
    int llo  = lane & 15, lhi = lane >> 4;
    f32x4 z = {0.f, 0.f, 0.f, 0.f};

    // ---- stage W1 frags once (2048 contiguous 16B chunks)
    #pragma unroll
    for (int p = 0; p < 8; ++p)
        ((u32x4*)w_s)[p * 256 + tid] = ((const u32x4*)w1f)[p * 256 + tid];

    #pragma unroll 1
    for (int s = 0; s < 2; ++s) {
        int task = blk * 2 + s;           // 0..1151; same b for s=0,1
        int b = task / 36;
        int t = task % 36;
        int I = 0;
        while (t >= 8 - I) { t -= 8 - I; ++I; }
        int J = I + t;

        if (s) __syncthreads();           // prev task's readers done

        // stage u/v tiles, swizzled: chunk = row*16 + (c ^ (row&7))
        {
            int row = tid >> 4;           // 0..15
            int c   = tid & 15;           // 16B chunk within 256B row
            int ga  = b * NA + ((row < 8) ? (I * 8 + row) : (J * 8 + (row & 7)));
            int sc  = row * 16 + (c ^ (row & 7));
            ((u32x4*)u_s)[sc] = ((const u32x4*)(u + (size_t)ga * NC))[c];
            ((u32x4*)v_s)[sc] = ((const u32x4*)(v + (size_t)ga * NC))[c];
        }
        __syncthreads();

        int r  = wave * 16 + llo;
        int il = r >> 3;                  // 0..7
        int jl = r & 7;                   // 0..7

        f32x4 acc0[8], acc1[8];
        #pragma unroll
        for (int nf = 0; nf < 8; ++nf) { acc0[nf] = z; acc1[nf] = z; }

        const f16x8* us = (const f16x8*)u_s;
        const f16x8* vs = (const f16x8*)v_s;
        const f16x8* wf = (const f16x8*)w_s;

        #pragma unroll
        for (int kk = 0; kk < 4; ++kk) {
            int kc  = kk * 4 + lhi;
            int scI = il * 16 + (kc ^ il);
            int scJ = (8 + jl) * 16 + (kc ^ jl);

            f16x8 uIv = us[scI];
            f16x8 vIv = vs[scI];
            f16x8 uJv = us[scJ];
            f16x8 vJv = vs[scJ];

            f16x8 s0 = uIv + vJv;
            f16x8 s1 = uJv + vIv;
            f16x8 h0, h1;
            #pragma unroll
            for (int e = 0; e < 8; ++e) {
                h0[e] = s0[e] < (_Float16)0 ? (_Float16)0 : s0[e];
                h1[e] = s1[e] < (_Float16)0 ? (_Float16)0 : s1[e];
            }

            #pragma unroll
            for (int nf = 0; nf < 8; ++nf) {
                f16x8 w = wf[(kk * 8 + nf) * 64 + lane];
                acc0[nf] = __builtin_amdgcn_mfma_f32_16x16x32_f16(
                    w, h0, acc0[nf], 0, 0, 0);
                acc1[nf] = __builtin_amdgcn_mfma_f32_16x16x32_f16(
                    w, h1, acc1[nf], 0, 0, 0);
            }
        }

        int Ig = I * 8 + il;
        int Jg = J * 8 + jl;
        float* p1 = out + ((size_t)b * 4096 + Ig * 64 + Jg) * 128 + lhi * 4;
        float* p2 = out + ((size_t)b * 4096 + Jg * 64 + Ig) * 128 + lhi * 4;
        bool mirror = (I != J);
        #pragma unroll
        for (int nf = 0; nf < 8; ++nf) {
            f32x4 bias = *(const f32x4*)(b1g + nf * 16 + lhi * 4);
            f32x4 val;
            #pragma unroll
            for (int e = 0; e < 4; ++e)
                val[e] = fmaxf(acc0[nf][e] + bias[e], 0.f) +
                         fmaxf(acc1[nf][e] + bias[e], 0.f);
            *(f32x4*)(p1 + nf * 16) = val;
            if (mirror)
                *(f32x4*)(p2 + nf * 16) = val;
        }
    }
}

extern "C" void kernel_launch(void* const* d_in, const int* in_sizes, int n_in,
                              void* d_out, int out_size, void* d_ws, size_t ws_size,
                              hipStream_t stream)
{
    (void)in_sizes; (void)n_in; (void)out_size; (void)ws_size;
    const float* x  = (const float*)d_in[0];
    const float* W0 = (const float*)d_in[1];
    const float* b0 = (const float*)d_in[2];
    const float* W1 = (const float*)d_in[3];
    const float* b1 = (const float*)d_in[4];
    float* out = (float*)d_out;

    _Float16* u   = (_Float16*)d_ws;                       // 0.5 MB
    _Float16* v   = u + (size_t)NB * NA * NC;              // 0.5 MB
    _Float16* w1f = v + (size_t)NB * NA * NC;              // 32 KB

    prep_kernel<<<264, 256, 0, stream>>>(x, W0, b0, W1, u, v, w1f);
    pair_mlp_kernel<<<576, 256, 0, stream>>>(b1, u, v, w1f, out);
}

// Round 13
// 29.657 us; speedup vs baseline: 2.6893x; 1.3571x over previous
//
#include <hip/hip_runtime.h>
#include <hip/hip_bf16.h>

typedef float    f32x4 __attribute__((ext_vector_type(4)));
typedef _Float16 f16x4 __attribute__((ext_vector_type(4)));
typedef _Float16 f16x8 __attribute__((ext_vector_type(8)));
typedef unsigned int   u32x4 __attribute__((ext_vector_type(4)));

#define NB 32
#define NA 64
#define NF 128
#define NC 128

// ---------------------------------------------------------------------------
// prep v3 — latency-parallel:
//  blocks 0..511: task (b, half, nq). Computes ALL 64 atoms x 16 channels
//    (c = nq*16..+16) of u (half=0) / v (half=1).
//    Wave w owns atoms w*16..w*16+16. A = x-frags (M=atoms), B = W0 slice
//    frags (N=channels) -> D[atom][ch]; 4 MFMAs/wave.
//    W0 slice gather: ONE 8-elem frag-slice per thread (8 scalar loads,
//    was 64 in R9) -> 4KB LDS, conflict-free f16x8 reads.
//    2+ blocks/CU, 8 waves/CU -> VMEM latency overlapped.
//  blocks 512..519: w1f = W1 in MFMA A-fragment order (unchanged).
// ---------------------------------------------------------------------------
__global__ __launch_bounds__(256) void prep_kernel(
    const float* __restrict__ x, const float* __restrict__ W0,
    const float* __restrict__ b0, const float* __restrict__ W1,
    _Float16* __restrict__ u, _Float16* __restrict__ v,
    _Float16* __restrict__ w1f)
{
    int blk = blockIdx.x, tid = threadIdx.x;
    int lane = tid & 63, wave = tid >> 6;
    int llo = lane & 15, lhi = lane >> 4;

    if (blk < 512) {
        __shared__ __align__(16) _Float16 w0l[4 * 64 * 8];   // 4 KB frag-major
        int b = blk >> 4, half = (blk >> 3) & 1, nq = blk & 7;

        // ---- x A-frags: this wave's 16 atoms (coalesced f32x4, issued first)
        const float* xrow = x + ((size_t)b * NA + wave * 16 + llo) * NF;
        f16x8 xf[4];
        #pragma unroll
        for (int kk = 0; kk < 4; ++kk) {
            f32x4 a0 = *(const f32x4*)(xrow + kk * 32 + lhi * 8);
            f32x4 a1 = *(const f32x4*)(xrow + kk * 32 + lhi * 8 + 4);
            #pragma unroll
            for (int e = 0; e < 4; ++e) {
                xf[kk][e]     = (_Float16)a0[e];
                xf[kk][e + 4] = (_Float16)a1[e];
            }
        }

        // ---- gather W0 slice -> frag LDS: one slice per thread (8 loads)
        {
            int kk = tid >> 6, ln = tid & 63;
            int k0 = half * 128 + kk * 32 + (ln >> 4) * 8;
            int c  = nq * 16 + (ln & 15);
            f16x8 o;
            #pragma unroll
            for (int e = 0; e < 8; ++e)
                o[e] = (_Float16)W0[(size_t)(k0 + e) * NC + c];
            *(f16x8*)(w0l + (size_t)tid * 8) = o;
        }
        __syncthreads();

        // ---- 4 MFMAs: D[atom_local][ch] over K=128
        f32x4 acc = {0.f, 0.f, 0.f, 0.f};
        #pragma unroll
        for (int kk = 0; kk < 4; ++kk) {
            f16x8 bw = *(const f16x8*)(w0l + (size_t)((kk * 64 + lane)) * 8);
            acc = __builtin_amdgcn_mfma_f32_16x16x32_f16(xf[kk], bw, acc, 0, 0, 0);
        }

        // ---- store: atom = wave*16 + lhi*4 + q, ch = nq*16 + llo
        _Float16* dst = half ? v : u;
        int c = nq * 16 + llo;
        float bb = half ? b0[c] : 0.f;
        #pragma unroll
        for (int q = 0; q < 4; ++q) {
            int atom = wave * 16 + lhi * 4 + q;
            dst[((size_t)b * NA + atom) * NC + c] = (_Float16)(acc[q] + bb);
        }
    } else {
        int fl   = (blk - 512) * 256 + tid;   // 0..2047
        int ln   = fl & 63;
        int frag = fl >> 6;                   // kk*8+nf
        int kk = frag >> 3, nf = frag & 7;
        int k0 = kk * 32 + (ln >> 4) * 8;
        int n  = nf * 16 + (ln & 15);
        f16x8 o;
        #pragma unroll
        for (int e = 0; e < 8; ++e)
            o[e] = (_Float16)W1[(size_t)(k0 + e) * NC + n];
        *(f16x8*)(w1f + (size_t)fl * 8) = o;
    }
}

// ---------------------------------------------------------------------------
// main: byte-identical to R9 (best known: ~17.5 us).
// block = (batch b, unordered 8x8 atom tile pair (I<=J)), 256 thr, 3/CU.
// ---------------------------------------------------------------------------
__global__ __launch_bounds__(256, 3) void pair_mlp_kernel(
    const float* __restrict__ b1g, const _Float16* __restrict__ u,
    const _Float16* __restrict__ v, const _Float16* __restrict__ w1f,
    float* __restrict__ out)
{
    __shared__ __align__(16) _Float16 u_s[16 * 128];    // 4 KB
    __shared__ __align__(16) _Float16 v_s[16 * 128];    // 4 KB
    __shared__ __align__(16) _Float16 w_s[32 * 64 * 8]; // 32 KB frag-major

    int blk = blockIdx.x;
    int b = blk / 36;
    int t = blk % 36;
    int I = 0;
    while (t >= 8 - I) { t -= 8 - I; ++I; }
    int J = I + t;

    int tid = threadIdx.x;

    // ---- stage u/v tiles, swizzled: chunk = row*16 + (c ^ (row&7))
    {
        int row = tid >> 4;            // 0..15
        int c   = tid & 15;            // 16B chunk within 256B row
        int ga  = b * NA + ((row < 8) ? (I * 8 + row) : (J * 8 + (row & 7)));
        int sc  = row * 16 + (c ^ (row & 7));
        ((u32x4*)u_s)[sc] = ((const u32x4*)(u + (size_t)ga * NC))[c];
        ((u32x4*)v_s)[sc] = ((const u32x4*)(v + (size_t)ga * NC))[c];
    }
    // ---- stage W1 frags: 2048 contiguous 16B chunks
    #pragma unroll
    for (int p = 0; p < 8; ++p)
        ((u32x4*)w_s)[p * 256 + tid] = ((const u32x4*)w1f)[p * 256 + tid];
    __syncthreads();

    int wave = tid >> 6;
    int lane = tid & 63;
    int llo  = lane & 15;
    int lhi  = lane >> 4;
    int r    = wave * 16 + llo;
    int il   = r >> 3;            // 0..7
    int jl   = r & 7;             // 0..7

    f32x4 acc0[8], acc1[8];
    f32x4 z = {0.f, 0.f, 0.f, 0.f};
    #pragma unroll
    for (int nf = 0; nf < 8; ++nf) { acc0[nf] = z; acc1[nf] = z; }

    const f16x8* us = (const f16x8*)u_s;
    const f16x8* vs = (const f16x8*)v_s;
    const f16x8* wf = (const f16x8*)w_s;

    #pragma unroll
    for (int kk = 0; kk < 4; ++kk) {
        int kc  = kk * 4 + lhi;
        int scI = il * 16 + (kc ^ il);          // il&7 == il
        int scJ = (8 + jl) * 16 + (kc ^ jl);    // (8+jl)&7 == jl

        f16x8 uIv = us[scI];
        f16x8 vIv = vs[scI];
        f16x8 uJv = us[scJ];
        f16x8 vJv = vs[scJ];

        f16x8 s0 = uIv + vJv;
        f16x8 s1 = uJv + vIv;
        f16x8 h0, h1;
        #pragma unroll
        for (int e = 0; e < 8; ++e) {
            h0[e] = s0[e] < (_Float16)0 ? (_Float16)0 : s0[e];
            h1[e] = s1[e] < (_Float16)0 ? (_Float16)0 : s1[e];
        }

        #pragma unroll
        for (int nf = 0; nf < 8; ++nf) {
            f16x8 w = wf[(kk * 8 + nf) * 64 + lane];
            acc0[nf] = __builtin_amdgcn_mfma_f32_16x16x32_f16(w, h0, acc0[nf], 0, 0, 0);
            acc1[nf] = __builtin_amdgcn_mfma_f32_16x16x32_f16(w, h1, acc1[nf], 0, 0, 0);
        }
    }

    int Ig = I * 8 + il;
    int Jg = J * 8 + jl;
    float* p1 = out + ((size_t)b * 4096 + Ig * 64 + Jg) * 128 + lhi * 4;
    float* p2 = out + ((size_t)b * 4096 + Jg * 64 + Ig) * 128 + lhi * 4;
    bool mirror = (I != J);
    #pragma unroll
    for (int nf = 0; nf < 8; ++nf) {
        f32x4 bias = *(const f32x4*)(b1g + nf * 16 + lhi * 4);
        f32x4 val;
        #pragma unroll
        for (int e = 0; e < 4; ++e)
            val[e] = fmaxf(acc0[nf][e] + bias[e], 0.f) +
                     fmaxf(acc1[nf][e] + bias[e], 0.f);
        *(f32x4*)(p1 + nf * 16) = val;
        if (mirror)
            *(f32x4*)(p2 + nf * 16) = val;
    }
}

extern "C" void kernel_launch(void* const* d_in, const int* in_sizes, int n_in,
                              void* d_out, int out_size, void* d_ws, size_t ws_size,
                              hipStream_t stream)
{
    (void)in_sizes; (void)n_in; (void)out_size; (void)ws_size;
    const float* x  = (const float*)d_in[0];
    const float* W0 = (const float*)d_in[1];
    const float* b0 = (const float*)d_in[2];
    const float* W1 = (const float*)d_in[3];
    const float* b1 = (const float*)d_in[4];
    float* out = (float*)d_out;

    _Float16* u   = (_Float16*)d_ws;                       // 0.5 MB
    _Float16* v   = u + (size_t)NB * NA * NC;              // 0.5 MB
    _Float16* w1f = v + (size_t)NB * NA * NC;              // 32 KB

    prep_kernel<<<520, 256, 0, stream>>>(x, W0, b0, W1, u, v, w1f);
    pair_mlp_kernel<<<32 * 36, 256, 0, stream>>>(b1, u, v, w1f, out);
}

// Round 14
// 29.572 us; speedup vs baseline: 2.6971x; 1.0029x over previous
//
#include <hip/hip_runtime.h>
#include <hip/hip_bf16.h>

typedef float    f32x4 __attribute__((ext_vector_type(4)));
typedef _Float16 f16x4 __attribute__((ext_vector_type(4)));
typedef _Float16 f16x8 __attribute__((ext_vector_type(8)));
typedef unsigned int   u32x4 __attribute__((ext_vector_type(4)));

#define NB 32
#define NA 64
#define NF 128
#define NC 128

// ---------------------------------------------------------------------------
// prep (R13, unchanged): latency-parallel u/v via f16 MFMA + w1f build.
// ---------------------------------------------------------------------------
__global__ __launch_bounds__(256) void prep_kernel(
    const float* __restrict__ x, const float* __restrict__ W0,
    const float* __restrict__ b0, const float* __restrict__ W1,
    _Float16* __restrict__ u, _Float16* __restrict__ v,
    _Float16* __restrict__ w1f)
{
    int blk = blockIdx.x, tid = threadIdx.x;
    int lane = tid & 63, wave = tid >> 6;
    int llo = lane & 15, lhi = lane >> 4;

    if (blk < 512) {
        __shared__ __align__(16) _Float16 w0l[4 * 64 * 8];   // 4 KB frag-major
        int b = blk >> 4, half = (blk >> 3) & 1, nq = blk & 7;

        const float* xrow = x + ((size_t)b * NA + wave * 16 + llo) * NF;
        f16x8 xf[4];
        #pragma unroll
        for (int kk = 0; kk < 4; ++kk) {
            f32x4 a0 = *(const f32x4*)(xrow + kk * 32 + lhi * 8);
            f32x4 a1 = *(const f32x4*)(xrow + kk * 32 + lhi * 8 + 4);
            #pragma unroll
            for (int e = 0; e < 4; ++e) {
                xf[kk][e]     = (_Float16)a0[e];
                xf[kk][e + 4] = (_Float16)a1[e];
            }
        }

        {
            int kk = tid >> 6, ln = tid & 63;
            int k0 = half * 128 + kk * 32 + (ln >> 4) * 8;
            int c  = nq * 16 + (ln & 15);
            f16x8 o;
            #pragma unroll
            for (int e = 0; e < 8; ++e)
                o[e] = (_Float16)W0[(size_t)(k0 + e) * NC + c];
            *(f16x8*)(w0l + (size_t)tid * 8) = o;
        }
        __syncthreads();

        f32x4 acc = {0.f, 0.f, 0.f, 0.f};
        #pragma unroll
        for (int kk = 0; kk < 4; ++kk) {
            f16x8 bw = *(const f16x8*)(w0l + (size_t)((kk * 64 + lane)) * 8);
            acc = __builtin_amdgcn_mfma_f32_16x16x32_f16(xf[kk], bw, acc, 0, 0, 0);
        }

        _Float16* dst = half ? v : u;
        int c = nq * 16 + llo;
        float bb = half ? b0[c] : 0.f;
        #pragma unroll
        for (int q = 0; q < 4; ++q) {
            int atom = wave * 16 + lhi * 4 + q;
            dst[((size_t)b * NA + atom) * NC + c] = (_Float16)(acc[q] + bb);
        }
    } else {
        int fl   = (blk - 512) * 256 + tid;   // 0..2047
        int ln   = fl & 63;
        int frag = fl >> 6;                   // kk*8+nf
        int kk = frag >> 3, nf = frag & 7;
        int k0 = kk * 32 + (ln >> 4) * 8;
        int n  = nf * 16 + (ln & 15);
        f16x8 o;
        #pragma unroll
        for (int e = 0; e < 8; ++e)
            o[e] = (_Float16)W1[(size_t)(k0 + e) * NC + n];
        *(f16x8*)(w1f + (size_t)fl * 8) = o;
    }
}

// ---------------------------------------------------------------------------
// main: IDENTICAL body to R13; ONLY change: __launch_bounds__(256,4)
// -> 4 blocks/CU (LDS 40KB x 4 = 160KB exactly), 16 waves/CU.
// ---------------------------------------------------------------------------
__global__ __launch_bounds__(256, 4) void pair_mlp_kernel(
    const float* __restrict__ b1g, const _Float16* __restrict__ u,
    const _Float16* __restrict__ v, const _Float16* __restrict__ w1f,
    float* __restrict__ out)
{
    __shared__ __align__(16) _Float16 u_s[16 * 128];    // 4 KB
    __shared__ __align__(16) _Float16 v_s[16 * 128];    // 4 KB
    __shared__ __align__(16) _Float16 w_s[32 * 64 * 8]; // 32 KB frag-major

    int blk = blockIdx.x;
    int b = blk / 36;
    int t = blk % 36;
    int I = 0;
    while (t >= 8 - I) { t -= 8 - I; ++I; }
    int J = I + t;

    int tid = threadIdx.x;

    {
        int row = tid >> 4;            // 0..15
        int c   = tid & 15;            // 16B chunk within 256B row
        int ga  = b * NA + ((row < 8) ? (I * 8 + row) : (J * 8 + (row & 7)));
        int sc  = row * 16 + (c ^ (row & 7));
        ((u32x4*)u_s)[sc] = ((const u32x4*)(u + (size_t)ga * NC))[c];
        ((u32x4*)v_s)[sc] = ((const u32x4*)(v + (size_t)ga * NC))[c];
    }
    #pragma unroll
    for (int p = 0; p < 8; ++p)
        ((u32x4*)w_s)[p * 256 + tid] = ((const u32x4*)w1f)[p * 256 + tid];
    __syncthreads();

    int wave = tid >> 6;
    int lane = tid & 63;
    int llo  = lane & 15;
    int lhi  = lane >> 4;
    int r    = wave * 16 + llo;
    int il   = r >> 3;            // 0..7
    int jl   = r & 7;             // 0..7

    f32x4 acc0[8], acc1[8];
    f32x4 z = {0.f, 0.f, 0.f, 0.f};
    #pragma unroll
    for (int nf = 0; nf < 8; ++nf) { acc0[nf] = z; acc1[nf] = z; }

    const f16x8* us = (const f16x8*)u_s;
    const f16x8* vs = (const f16x8*)v_s;
    const f16x8* wf = (const f16x8*)w_s;

    #pragma unroll
    for (int kk = 0; kk < 4; ++kk) {
        int kc  = kk * 4 + lhi;
        int scI = il * 16 + (kc ^ il);          // il&7 == il
        int scJ = (8 + jl) * 16 + (kc ^ jl);    // (8+jl)&7 == jl

        f16x8 uIv = us[scI];
        f16x8 vIv = vs[scI];
        f16x8 uJv = us[scJ];
        f16x8 vJv = vs[scJ];

        f16x8 s0 = uIv + vJv;
        f16x8 s1 = uJv + vIv;
        f16x8 h0, h1;
        #pragma unroll
        for (int e = 0; e < 8; ++e) {
            h0[e] = s0[e] < (_Float16)0 ? (_Float16)0 : s0[e];
            h1[e] = s1[e] < (_Float16)0 ? (_Float16)0 : s1[e];
        }

        #pragma unroll
        for (int nf = 0; nf < 8; ++nf) {
            f16x8 w = wf[(kk * 8 + nf) * 64 + lane];
            acc0[nf] = __builtin_amdgcn_mfma_f32_16x16x32_f16(w, h0, acc0[nf], 0, 0, 0);
            acc1[nf] = __builtin_amdgcn_mfma_f32_16x16x32_f16(w, h1, acc1[nf], 0, 0, 0);
        }
    }

    int Ig = I * 8 + il;
    int Jg = J * 8 + jl;
    float* p1 = out + ((size_t)b * 4096 + Ig * 64 + Jg) * 128 + lhi * 4;
    float* p2 = out + ((size_t)b * 4096 + Jg * 64 + Ig) * 128 + lhi * 4;
    bool mirror = (I != J);
    #pragma unroll
    for (int nf = 0; nf < 8; ++nf) {
        f32x4 bias = *(const f32x4*)(b1g + nf * 16 + lhi * 4);
        f32x4 val;
        #pragma unroll
        for (int e = 0; e < 4; ++e)
            val[e] = fmaxf(acc0[nf][e] + bias[e], 0.f) +
                     fmaxf(acc1[nf][e] + bias[e], 0.f);
        *(f32x4*)(p1 + nf * 16) = val;
        if (mirror)
            *(f32x4*)(p2 + nf * 16) = val;
    }
}

extern "C" void kernel_launch(void* const* d_in, const int* in_sizes, int n_in,
                              void* d_out, int out_size, void* d_ws, size_t ws_size,
                              hipStream_t stream)
{
    (void)in_sizes; (void)n_in; (void)out_size; (void)ws_size;
    const float* x  = (const float*)d_in[0];
    const float* W0 = (const float*)d_in[1];
    const float* b0 = (const float*)d_in[2];
    const float* W1 = (const float*)d_in[3];
    const float* b1 = (const float*)d_in[4];
    float* out = (float*)d_out;

    _Float16* u   = (_Float16*)d_ws;                       // 0.5 MB
    _Float16* v   = u + (size_t)NB * NA * NC;              // 0.5 MB
    _Float16* w1f = v + (size_t)NB * NA * NC;              // 32 KB

    prep_kernel<<<520, 256, 0, stream>>>(x, W0, b0, W1, u, v, w1f);
    pair_mlp_kernel<<<32 * 36, 256, 0, stream>>>(b1, u, v, w1f, out);
}